// Round 4
// baseline (162.989 us; speedup 1.0000x reference)
//
#include <hip/hip_runtime.h>
#include <cstdint>
#include <cstddef>

// Problem constants
#define B_DIM 4096   // batch (GEMM M)
#define S_DIM 2048   // states (GEMM N)
#define D_DIM 2496   // feature dim (GEMM K) = 78 * 32

// GEMM tiling: 128x128 block, 4 waves each owning 64x64 via 2x2
// mfma_f32_32x32x16_bf16, BK=32, XOR-swizzled LDS chunk layout.
// R3 lesson: kernel is LDS-read-pipe bound (4 waves/SIMD == 2 waves/SIMD
// exactly); fix the pipe, not the occupancy.
#define BM 128
#define BN 128
#define BK 32

typedef __attribute__((ext_vector_type(8)))  short short8;
typedef __attribute__((ext_vector_type(16))) float f32x16;

// ---------------------------------------------------------------------------
// fp32 -> bf16 round-to-nearest-even (inputs are positive uniforms; no NaN)
__device__ __forceinline__ unsigned short f2bf(float f) {
    union { float f; unsigned int u; } v; v.f = f;
    unsigned int r = (v.u + 0x7fffu + ((v.u >> 16) & 1u)) >> 16;
    return (unsigned short)r;
}

struct __attribute__((aligned(16))) us8 { unsigned short h[8]; };

// ---------------------------------------------------------------------------
// Prep, wave-per-row: each 64-lane wave converts one row to bf16 and computes
// its fp32 squared norm via shuffle reduce. No LDS, no barriers.
__global__ __launch_bounds__(256) void prep_kernel(
    const float* __restrict__ X, const float* __restrict__ Mx,
    unsigned short* __restrict__ Xb, unsigned short* __restrict__ Mb,
    float* __restrict__ xsq, float* __restrict__ msq)
{
    const int lane = threadIdx.x & 63;
    const int row  = blockIdx.x * 4 + (threadIdx.x >> 6);

    const float* src; unsigned short* dst; float* sq;
    if (row < B_DIM) {
        src = X + (size_t)row * D_DIM; dst = Xb + (size_t)row * D_DIM; sq = xsq + row;
    } else {
        const int r = row - B_DIM;
        src = Mx + (size_t)r * D_DIM; dst = Mb + (size_t)r * D_DIM; sq = msq + r;
    }

    const float4* s4 = (const float4*)src;
    us8* d8 = (us8*)dst;
    float acc = 0.f;
    for (int i = lane; i < D_DIM / 8; i += 64) {
        float4 a = s4[2 * i], b = s4[2 * i + 1];
        acc += a.x * a.x + a.y * a.y + a.z * a.z + a.w * a.w;
        acc += b.x * b.x + b.y * b.y + b.z * b.z + b.w * b.w;
        us8 h;
        h.h[0] = f2bf(a.x); h.h[1] = f2bf(a.y); h.h[2] = f2bf(a.z); h.h[3] = f2bf(a.w);
        h.h[4] = f2bf(b.x); h.h[5] = f2bf(b.y); h.h[6] = f2bf(b.z); h.h[7] = f2bf(b.w);
        d8[i] = h;
    }
    #pragma unroll
    for (int off = 32; off > 0; off >>= 1)
        acc += __shfl_down(acc, off, 64);
    if (lane == 0) *sq = acc;
}

// ---------------------------------------------------------------------------
// global -> LDS direct (async) load, 16 B per lane; dest = wave-uniform base +
// lane*16 (no per-lane scatter), so LDS layout is contiguous in lane order.
__device__ __forceinline__ void gld_lds16(const unsigned short* g, unsigned short* l) {
    __builtin_amdgcn_global_load_lds(
        (const __attribute__((address_space(1))) unsigned int*)g,
        (__attribute__((address_space(3))) unsigned int*)l,
        16, 0, 0);
}

// ---------------------------------------------------------------------------
// C[row,col] = (2*sum_k A[row,k]*B[col,k] - xsq[row] - msq[col]) / 500
// A: [4096, 2496] bf16 row-major; Bt: [2048, 2496] bf16 row-major (NT GEMM).
//
// LDS layout: tile row r (BK=32 bf16 = 64 B = four 16-B chunks); the chunk
// holding global k-segment g lives at slot (g ^ (r&3)). Staging lane
// i = 4*row_local + c loads global chunk (c ^ (row&3)) so the contiguous
// lane-order LDS write produces exactly this layout. Fragment reads then hit
// 4 bank-quads 2-way (free) instead of 2 quads 4-way (the R1-R3 conflict).
__global__ __launch_bounds__(256) void gemm_kernel(
    const unsigned short* __restrict__ A,
    const unsigned short* __restrict__ Bt,
    const float* __restrict__ xsq, const float* __restrict__ msq,
    float* __restrict__ C)
{
    constexpr int N = S_DIM;
    constexpr int K = D_DIM;

    __shared__ __align__(16) unsigned short As[BM * BK];  // 8 KB
    __shared__ __align__(16) unsigned short Bs[BN * BK];  // 8 KB

    const int tid  = threadIdx.x;
    const int lane = tid & 63;
    const int wave = tid >> 6;       // 4 waves
    const int wm = wave >> 1;        // wave row (0..1) -> 64 rows
    const int wn = wave & 1;         // wave col (0..1) -> 64 cols
    const int bm = blockIdx.y;
    const int bn = blockIdx.x;

    // Staging: one issue = 16 rows x 4 chunks; lane i -> row (i>>2), chunk
    // (i&3), which must contain global k-segment (i&3) ^ ((i>>2)&3).
    const int srow = wave * 32 + (lane >> 2);
    const int skk  = (((lane & 3) ^ ((lane >> 2) & 3))) * 8;
    const unsigned short* gA = A  + (size_t)(bm * BM + srow) * K + skk;
    const unsigned short* gB = Bt + (size_t)(bn * BN + srow) * K + skk;
    unsigned short* lA0 = &As[(wave * 32     ) * BK];
    unsigned short* lA1 = &As[(wave * 32 + 16) * BK];
    unsigned short* lB0 = &Bs[(wave * 32     ) * BK];
    unsigned short* lB1 = &Bs[(wave * 32 + 16) * BK];

    f32x16 acc[2][2] = {};

    // mfma_32x32x16 A/B fragment: m (or n) = lane&31, k = (lane>>5)*8 + j.
    const int l31 = lane & 31;
    const int h   = lane >> 5;          // k-half
    const int rk  = l31 & 3;            // row&3 (tile row bases are %4 == 0)

    for (int k0 = 0; k0 < K; k0 += BK) {
        __syncthreads();   // previous tile fully consumed
        gld_lds16(gA,                  lA0);
        gld_lds16(gA + (size_t)16 * K, lA1);
        gld_lds16(gB,                  lB0);
        gld_lds16(gB + (size_t)16 * K, lB1);
        gA += BK; gB += BK;
        __syncthreads();   // drains vmcnt(0) before barrier

        #pragma unroll
        for (int s = 0; s < 2; ++s) {      // two k-steps of 16
            const int g  = s * 2 + h;       // global 8-elem k-segment index
            const int sw = (g ^ rk) * 8;    // swizzled element offset in row
            short8 a0 = *(const short8*)&As[(wm * 64      + l31) * BK + sw];
            short8 a1 = *(const short8*)&As[(wm * 64 + 32 + l31) * BK + sw];
            short8 b0 = *(const short8*)&Bs[(wn * 64      + l31) * BK + sw];
            short8 b1 = *(const short8*)&Bs[(wn * 64 + 32 + l31) * BK + sw];
            acc[0][0] = __builtin_amdgcn_mfma_f32_32x32x16_bf16(a0, b0, acc[0][0], 0, 0, 0);
            acc[0][1] = __builtin_amdgcn_mfma_f32_32x32x16_bf16(a0, b1, acc[0][1], 0, 0, 0);
            acc[1][0] = __builtin_amdgcn_mfma_f32_32x32x16_bf16(a1, b0, acc[1][0], 0, 0, 0);
            acc[1][1] = __builtin_amdgcn_mfma_f32_32x32x16_bf16(a1, b1, acc[1][1], 0, 0, 0);
        }
    }

    // Epilogue. 32x32 C/D layout (m74/m101): col = lane&31,
    // row = (reg&3) + 8*(reg>>2) + 4*(lane>>5).
    const int rowb = bm * BM + wm * 64 + 4 * h;
    const int colb = bn * BN + wn * 64 + l31;
    #pragma unroll
    for (int ni = 0; ni < 2; ++ni) {
        const float ms = msq[colb + ni * 32];
        #pragma unroll
        for (int mi = 0; mi < 2; ++mi) {
            #pragma unroll
            for (int q = 0; q < 4; ++q) {
                #pragma unroll
                for (int j = 0; j < 4; ++j) {
                    const int reg = q * 4 + j;
                    const int row = rowb + mi * 32 + q * 8 + j;
                    const float v = (2.0f * acc[mi][ni][reg] - xsq[row] - ms)
                                    * (1.0f / 500.0f);
                    C[(size_t)row * N + colb + ni * 32] = v;
                }
            }
        }
    }
}

// ---------------------------------------------------------------------------
extern "C" void kernel_launch(void* const* d_in, const int* in_sizes, int n_in,
                              void* d_out, int out_size, void* d_ws, size_t ws_size,
                              hipStream_t stream) {
    const float* X  = (const float*)d_in[0];  // [4096, 2496]
    const float* Mx = (const float*)d_in[1];  // [2048, 2496]
    float* out = (float*)d_out;               // [4096, 2048]

    // Workspace layout (~30.7 MB): Xb bf16 | Mb bf16 | xsq f32 | msq f32
    unsigned short* Xb = (unsigned short*)d_ws;
    unsigned short* Mb = Xb + (size_t)B_DIM * D_DIM;
    float* xsq = (float*)(Mb + (size_t)S_DIM * D_DIM);
    float* msq = xsq + B_DIM;

    prep_kernel<<<(B_DIM + S_DIM) / 4, 256, 0, stream>>>(X, Mx, Xb, Mb, xsq, msq);

    dim3 grid(S_DIM / BN, B_DIM / BM);  // (16, 32) = 512 blocks -> 2/CU
    gemm_kernel<<<grid, 256, 0, stream>>>(Xb, Mb, xsq, msq, out);
}

// Round 5
// 131.161 us; speedup vs baseline: 1.2427x; 1.2427x over previous
//
#include <hip/hip_runtime.h>
#include <cstdint>
#include <cstddef>

// Problem constants
#define B_DIM 4096   // batch (GEMM M)
#define S_DIM 2048   // states (GEMM N)
#define D_DIM 2496   // feature dim (GEMM K) = 39 * 64
#define QSCALE 127.0f
#define QSCALE2 16129.0f   // 127^2

// GEMM tiling: R1's exact schedule (128x128 block, 4 waves 2x2, each 64x64 via
// 4x4 MFMA, 8 ds_read_b128 + 4 gld_lds16 per wave-iter) but in INT8 with
// BK=64 and mfma_i32_16x16x64_i8. R1/R3 proved the LDS read pipe is the wall
// (64 KB/CU/iter at 85 B/cyc ~= whole iter); i8 halves LDS bytes/FLOP and
// MFMA cyc/FLOP simultaneously: 39 iters instead of 78 at the same per-iter
// cost. R4's swizzle reverted (conflicts doubled; R1's 8-quad x 8-lane
// pattern at 4 cyc/instr is the known-good one).
#define BM 128
#define BN 128
#define BK 64

typedef __attribute__((ext_vector_type(4))) int int4v;

// ---------------------------------------------------------------------------
struct __attribute__((aligned(8))) uc8 { unsigned char c[8]; };

// Prep, wave-per-row: quantize one row to u8 in [0,127] (RTN) and compute the
// EXACT fp32 squared norm of the original floats via shuffle reduce.
__global__ __launch_bounds__(256) void prep_kernel(
    const float* __restrict__ X, const float* __restrict__ Mx,
    unsigned char* __restrict__ Xq, unsigned char* __restrict__ Mq,
    float* __restrict__ xsq, float* __restrict__ msq)
{
    const int lane = threadIdx.x & 63;
    const int row  = blockIdx.x * 4 + (threadIdx.x >> 6);

    const float* src; unsigned char* dst; float* sq;
    if (row < B_DIM) {
        src = X + (size_t)row * D_DIM; dst = Xq + (size_t)row * D_DIM; sq = xsq + row;
    } else {
        const int r = row - B_DIM;
        src = Mx + (size_t)r * D_DIM; dst = Mq + (size_t)r * D_DIM; sq = msq + r;
    }

    const float4* s4 = (const float4*)src;
    uc8* d8 = (uc8*)dst;
    float acc = 0.f;
    for (int i = lane; i < D_DIM / 8; i += 64) {
        float4 a = s4[2 * i], b = s4[2 * i + 1];
        acc += a.x * a.x + a.y * a.y + a.z * a.z + a.w * a.w;
        acc += b.x * b.x + b.y * b.y + b.z * b.z + b.w * b.w;
        uc8 q;
        q.c[0] = (unsigned char)__float2int_rn(a.x * QSCALE);
        q.c[1] = (unsigned char)__float2int_rn(a.y * QSCALE);
        q.c[2] = (unsigned char)__float2int_rn(a.z * QSCALE);
        q.c[3] = (unsigned char)__float2int_rn(a.w * QSCALE);
        q.c[4] = (unsigned char)__float2int_rn(b.x * QSCALE);
        q.c[5] = (unsigned char)__float2int_rn(b.y * QSCALE);
        q.c[6] = (unsigned char)__float2int_rn(b.z * QSCALE);
        q.c[7] = (unsigned char)__float2int_rn(b.w * QSCALE);
        d8[i] = q;
    }
    #pragma unroll
    for (int off = 32; off > 0; off >>= 1)
        acc += __shfl_down(acc, off, 64);
    if (lane == 0) *sq = acc;
}

// ---------------------------------------------------------------------------
// global -> LDS direct (async) load, 16 B per lane; dest = wave-uniform base +
// lane*16 (no per-lane scatter), so LDS layout is contiguous in lane order.
__device__ __forceinline__ void gld_lds16(const unsigned char* g, unsigned char* l) {
    __builtin_amdgcn_global_load_lds(
        (const __attribute__((address_space(1))) unsigned int*)g,
        (__attribute__((address_space(3))) unsigned int*)l,
        16, 0, 0);
}

// ---------------------------------------------------------------------------
// C[row,col] = (2*cross - xsq[row] - msq[col]) / 500, cross = acc_i32/127^2.
// A: [4096, 2496] u8 row-major; Bt: [2048, 2496] u8 row-major (NT GEMM).
// Values are 0..127 so signed-i8 MFMA sees them exactly.
__global__ __launch_bounds__(256) void gemm_kernel(
    const unsigned char* __restrict__ A,
    const unsigned char* __restrict__ Bt,
    const float* __restrict__ xsq, const float* __restrict__ msq,
    float* __restrict__ C)
{
    constexpr int N = S_DIM;
    constexpr int K = D_DIM;   // bytes per row

    __shared__ __align__(16) unsigned char As[BM * BK];  // 8 KB
    __shared__ __align__(16) unsigned char Bs[BN * BK];  // 8 KB

    const int tid  = threadIdx.x;
    const int lane = tid & 63;
    const int wave = tid >> 6;       // 4 waves
    const int wm = wave >> 1;        // wave row (0..1) -> 64 rows
    const int wn = wave & 1;         // wave col (0..1) -> 64 cols
    const int bm = blockIdx.y;
    const int bn = blockIdx.x;

    // Staging: one gld_lds16 issue = 16 rows x 64 B (64 lanes x 16 B).
    // Lane i -> row (i>>2), 16-B chunk (i&3); LDS dest base+lane*16 equals
    // row*64 + chunk*16 (contiguous, unpadded). 2496 % 16 == 0 so global
    // chunk addresses are 16-B aligned.
    const int srow = wave * 32 + (lane >> 2);
    const int skk  = (lane & 3) * 16;
    const unsigned char* gA = A  + (size_t)(bm * BM + srow) * K + skk;
    const unsigned char* gB = Bt + (size_t)(bn * BN + srow) * K + skk;
    unsigned char* lA0 = &As[(wave * 32     ) * BK];
    unsigned char* lA1 = &As[(wave * 32 + 16) * BK];
    unsigned char* lB0 = &Bs[(wave * 32     ) * BK];
    unsigned char* lB1 = &Bs[(wave * 32 + 16) * BK];

    int4v acc[4][4] = {};

    // i8 16x16x64 A/B fragment (by analogy with verified bf16 16x16x32
    // k=(lane>>4)*8+j): m (or n) = lane&15, k = (lane>>4)*16 + j, j=0..15
    // contiguous bytes -> one ds_read_b128 per fragment.
    const int ko = (lane >> 4) * 16;  // byte offset within 64-B row
    const int fr = lane & 15;

    for (int k0 = 0; k0 < K; k0 += BK) {   // 39 iterations
        __syncthreads();   // previous tile fully consumed
        gld_lds16(gA,                  lA0);
        gld_lds16(gA + (size_t)16 * K, lA1);
        gld_lds16(gB,                  lB0);
        gld_lds16(gB + (size_t)16 * K, lB1);
        gA += BK; gB += BK;
        __syncthreads();   // drains vmcnt(0) before barrier

        int4v af[4], bfr[4];
        #pragma unroll
        for (int i = 0; i < 4; ++i) {
            af[i]  = *(const int4v*)&As[(wm * 64 + i * 16 + fr) * BK + ko];
            bfr[i] = *(const int4v*)&Bs[(wn * 64 + i * 16 + fr) * BK + ko];
        }
        #pragma unroll
        for (int mi = 0; mi < 4; ++mi)
            #pragma unroll
            for (int ni = 0; ni < 4; ++ni)
                acc[mi][ni] = __builtin_amdgcn_mfma_i32_16x16x64_i8(
                    af[mi], bfr[ni], acc[mi][ni], 0, 0, 0);
    }

    // Epilogue. C/D layout is dtype-independent (m121-m128): col = lane&15,
    // row = (lane>>4)*4 + reg. cross = acc/127^2 in fp32 (acc <= 4.03e7,
    // i32->f32 rounding contributes <1e-6 to the output).
    const int row0 = bm * BM + wm * 64 + (lane >> 4) * 4;
    const int col0 = bn * BN + wn * 64 + fr;
    float ms[4];
    #pragma unroll
    for (int ni = 0; ni < 4; ++ni) ms[ni] = msq[col0 + ni * 16];
    #pragma unroll
    for (int mi = 0; mi < 4; ++mi) {
        #pragma unroll
        for (int r = 0; r < 4; ++r) {
            const int row = row0 + mi * 16 + r;
            const float xs = xsq[row];
            #pragma unroll
            for (int ni = 0; ni < 4; ++ni) {
                const float cr2 = (float)acc[mi][ni][r] * (2.0f / QSCALE2);
                const float v = (cr2 - xs - ms[ni]) * (1.0f / 500.0f);
                C[(size_t)row * N + col0 + ni * 16] = v;
            }
        }
    }
}

// ---------------------------------------------------------------------------
extern "C" void kernel_launch(void* const* d_in, const int* in_sizes, int n_in,
                              void* d_out, int out_size, void* d_ws, size_t ws_size,
                              hipStream_t stream) {
    const float* X  = (const float*)d_in[0];  // [4096, 2496]
    const float* Mx = (const float*)d_in[1];  // [2048, 2496]
    float* out = (float*)d_out;               // [4096, 2048]

    // Workspace layout (~15.4 MB): Xq u8 | Mq u8 | xsq f32 | msq f32
    unsigned char* Xq = (unsigned char*)d_ws;
    unsigned char* Mq = Xq + (size_t)B_DIM * D_DIM;
    float* xsq = (float*)(Mq + (size_t)S_DIM * D_DIM);
    float* msq = xsq + B_DIM;

    prep_kernel<<<(B_DIM + S_DIM) / 4, 256, 0, stream>>>(X, Mx, Xq, Mq, xsq, msq);

    dim3 grid(S_DIM / BN, B_DIM / BM);  // (16, 32) = 512 blocks -> 2/CU
    gemm_kernel<<<grid, 256, 0, stream>>>(Xq, Mq, xsq, msq, out);
}